// Round 1
// baseline (808.509 us; speedup 1.0000x reference)
//
#include <hip/hip_runtime.h>
#include <math.h>

#define NB 32768
#define ND 768
#define NC 474
#define NE 3
#define NH 128

// ---------------------------------------------------------------------------
// Kernel 1: fused selector MLP (fp64 accumulation) + argmax bucket + LN stats
// Block: 256 threads, 64 rows per block.
// ---------------------------------------------------------------------------
__global__ __launch_bounds__(256) void selector_kernel(
    const float* __restrict__ x, const float* __restrict__ gum,
    const float* __restrict__ w1, const float* __restrict__ b1,
    const float* __restrict__ w2, const float* __restrict__ b2,
    float2* __restrict__ murs, int* __restrict__ counts,
    int* __restrict__ rowlist)
{
    const int row0 = blockIdx.x * 64;
    const int t = threadIdx.x;
    const int tx = t & 31;          // col group: cols tx*4 .. tx*4+3 (of 128)
    const int ty = t >> 5;          // row group: rows ty*8 .. ty*8+7 (of 64)

    __shared__ float Xs[16][65];
    __shared__ float Ws[16 * 128];
    __shared__ double logits_s[64][3];

    double acc[8][4];
    #pragma unroll
    for (int r = 0; r < 8; ++r)
        #pragma unroll
        for (int j = 0; j < 4; ++j) acc[r][j] = 0.0;

    const int li = t >> 2;          // row 0..63 for A-tile load
    const int lk = (t & 3) << 2;    // k offset 0..12

    for (int k0 = 0; k0 < ND; k0 += 16) {
        // A tile (transposed into LDS)
        const float4 av = *(const float4*)(x + (size_t)(row0 + li) * ND + k0 + lk);
        Xs[lk + 0][li] = av.x;
        Xs[lk + 1][li] = av.y;
        Xs[lk + 2][li] = av.z;
        Xs[lk + 3][li] = av.w;
        // W1 tile: 16x128 is contiguous -> straight vector copy
        const float4* wsrc = (const float4*)(w1 + (size_t)k0 * NH);
        ((float4*)Ws)[t] = wsrc[t];
        ((float4*)Ws)[t + 256] = wsrc[t + 256];
        __syncthreads();
        #pragma unroll
        for (int kk = 0; kk < 16; ++kk) {
            const float4 b4 = *(const float4*)&Ws[kk * 128 + tx * 4];
            const double b0 = (double)b4.x, bq1 = (double)b4.y;
            const double bq2 = (double)b4.z, bq3 = (double)b4.w;
            #pragma unroll
            for (int r = 0; r < 8; ++r) {
                const double a = (double)Xs[kk][ty * 8 + r];
                acc[r][0] += a * b0;
                acc[r][1] += a * bq1;
                acc[r][2] += a * bq2;
                acc[r][3] += a * bq3;
            }
        }
        __syncthreads();
    }

    // logits partials: relu(h + b1) @ W2 (still fp64)
    double part[8][3];
    #pragma unroll
    for (int r = 0; r < 8; ++r) { part[r][0] = 0; part[r][1] = 0; part[r][2] = 0; }
    #pragma unroll
    for (int j = 0; j < 4; ++j) {
        const int c = tx * 4 + j;
        const double bb  = (double)b1[c];
        const double w0  = (double)w2[c * 3 + 0];
        const double wq1 = (double)w2[c * 3 + 1];
        const double wq2 = (double)w2[c * 3 + 2];
        #pragma unroll
        for (int r = 0; r < 8; ++r) {
            double h = acc[r][j] + bb;
            h = h > 0.0 ? h : 0.0;
            part[r][0] += h * w0;
            part[r][1] += h * wq1;
            part[r][2] += h * wq2;
        }
    }
    // butterfly reduce across the 32 tx lanes (stays inside each 32-half)
    #pragma unroll
    for (int m = 16; m >= 1; m >>= 1) {
        #pragma unroll
        for (int r = 0; r < 8; ++r) {
            part[r][0] += __shfl_xor(part[r][0], m);
            part[r][1] += __shfl_xor(part[r][1], m);
            part[r][2] += __shfl_xor(part[r][2], m);
        }
    }
    if (tx == 0) {
        #pragma unroll
        for (int r = 0; r < 8; ++r) {
            logits_s[ty * 8 + r][0] = part[r][0];
            logits_s[ty * 8 + r][1] = part[r][1];
            logits_s[ty * 8 + r][2] = part[r][2];
        }
    }
    __syncthreads();

    // LN stats: 4 threads per row, 192 contiguous elems each
    {
        const int r = t >> 2, q = t & 3;
        const float4* xp = (const float4*)(x + (size_t)(row0 + r) * ND + q * 192);
        float s1 = 0.f, s2 = 0.f;
        #pragma unroll 4
        for (int i = 0; i < 48; ++i) {
            const float4 v = xp[i];
            s1 += v.x + v.y + v.z + v.w;
            s2 += v.x * v.x + v.y * v.y + v.z * v.z + v.w * v.w;
        }
        s1 += __shfl_xor(s1, 1); s2 += __shfl_xor(s2, 1);
        s1 += __shfl_xor(s1, 2); s2 += __shfl_xor(s2, 2);
        if (q == 0) {
            const float mu = s1 * (1.0f / 768.0f);
            const float var = s2 * (1.0f / 768.0f) - mu * mu;
            const float rs = 1.0f / sqrtf(var + 1e-5f);
            murs[row0 + r] = make_float2(mu, rs);
        }
    }

    // argmax(logits + b2 + gumbel), first-index-wins, bucket append
    if (t < 64) {
        const int r = t;
        const int grow = row0 + r;
        double best = 0.0; int be = 0;
        #pragma unroll
        for (int e = 0; e < NE; ++e) {
            const double z = logits_s[r][e] + (double)b2[e] + (double)gum[grow * 3 + e];
            if (e == 0 || z > best) { best = z; be = e; }
        }
        const int pos = atomicAdd(&counts[be], 1);
        rowlist[be * NB + pos] = grow;
    }
}

// ---------------------------------------------------------------------------
// Kernel 2: grouped head GEMM. out[row] = (LN(x[row])*gamma[e]+beta[e]) @ hw[e] + hb[e]
// Grid: (col-chunks=8, row-chunks=512, experts=3), 256 threads, 64x64x16 tile.
// ---------------------------------------------------------------------------
__global__ __launch_bounds__(256) void head_kernel(
    const float* __restrict__ x, const float2* __restrict__ murs,
    const float* __restrict__ gamma, const float* __restrict__ beta,
    const float* __restrict__ hw, const float* __restrict__ hb,
    const int* __restrict__ counts, const int* __restrict__ rowlist,
    float* __restrict__ out)
{
    const int e = blockIdx.z;
    const int cnt = counts[e];
    const int rc0 = blockIdx.y * 64;
    if (rc0 >= cnt) return;
    const int c0 = blockIdx.x * 64;
    const int t = threadIdx.x;
    const int tx = t & 15;          // cols tx*4 .. +3
    const int ty = t >> 4;          // rows ty*4 .. +3

    __shared__ float As[16][65];
    __shared__ float Bs[16][68];

    float acc[4][4] = {};

    // A-load mapping: thread loads row ai, k block ak..ak+3
    const int ai = t >> 2;
    const int ak = (t & 3) << 2;
    const int ridx = rc0 + ai;
    const bool av = ridx < cnt;
    int arow = 0; float mu = 0.f, rs = 0.f;
    if (av) {
        arow = rowlist[e * NB + ridx];
        const float2 mr = murs[arow];
        mu = mr.x; rs = mr.y;
    }
    const float* xrow = x + (size_t)arow * ND;
    const float* gmp = gamma + e * ND;
    const float* btp = beta + e * ND;

    // B-load mapping
    const int bk = t >> 4;          // 0..15
    const int bc = (t & 15) << 2;   // 0..60
    const float* hwe = hw + (size_t)e * ND * NC;

    for (int k0 = 0; k0 < ND; k0 += 16) {
        float4 xv = make_float4(0.f, 0.f, 0.f, 0.f);
        if (av) xv = *(const float4*)(xrow + k0 + ak);
        const float4 gv = *(const float4*)(gmp + k0 + ak);
        const float4 bv = *(const float4*)(btp + k0 + ak);
        As[ak + 0][ai] = av ? ((xv.x - mu) * rs * gv.x + bv.x) : 0.f;
        As[ak + 1][ai] = av ? ((xv.y - mu) * rs * gv.y + bv.y) : 0.f;
        As[ak + 2][ai] = av ? ((xv.z - mu) * rs * gv.z + bv.z) : 0.f;
        As[ak + 3][ai] = av ? ((xv.w - mu) * rs * gv.w + bv.w) : 0.f;

        const int c = c0 + bc;
        const float* bsrc = hwe + (size_t)(k0 + bk) * NC + c;
        float2 p0 = make_float2(0.f, 0.f), p1 = make_float2(0.f, 0.f);
        if (c < NC) p0 = *(const float2*)bsrc;
        if (c + 2 < NC) p1 = *(const float2*)(bsrc + 2);
        Bs[bk][bc + 0] = p0.x; Bs[bk][bc + 1] = p0.y;
        Bs[bk][bc + 2] = p1.x; Bs[bk][bc + 3] = p1.y;
        __syncthreads();
        #pragma unroll
        for (int kk = 0; kk < 16; ++kk) {
            const float4 b4 = *(const float4*)&Bs[kk][tx * 4];
            #pragma unroll
            for (int r = 0; r < 4; ++r) {
                const float a = As[kk][ty * 4 + r];
                acc[r][0] = fmaf(a, b4.x, acc[r][0]);
                acc[r][1] = fmaf(a, b4.y, acc[r][1]);
                acc[r][2] = fmaf(a, b4.z, acc[r][2]);
                acc[r][3] = fmaf(a, b4.w, acc[r][3]);
            }
        }
        __syncthreads();
    }

    #pragma unroll
    for (int r = 0; r < 4; ++r) {
        const int ridx2 = rc0 + ty * 4 + r;
        if (ridx2 >= cnt) continue;
        const int orow = rowlist[e * NB + ridx2];
        float* op = out + (size_t)orow * NC;
        #pragma unroll
        for (int j = 0; j < 4; ++j) {
            const int c = c0 + tx * 4 + j;
            if (c < NC) op[c] = acc[r][j] + hb[e * NC + c];
        }
    }
}

extern "C" void kernel_launch(void* const* d_in, const int* in_sizes, int n_in,
                              void* d_out, int out_size, void* d_ws, size_t ws_size,
                              hipStream_t stream) {
    const float* x     = (const float*)d_in[0];
    const float* gum   = (const float*)d_in[1];
    const float* w1    = (const float*)d_in[2];
    const float* b1    = (const float*)d_in[3];
    const float* w2    = (const float*)d_in[4];
    const float* b2    = (const float*)d_in[5];
    const float* gamma = (const float*)d_in[6];
    const float* beta  = (const float*)d_in[7];
    const float* hw    = (const float*)d_in[8];
    const float* hb    = (const float*)d_in[9];
    float* out = (float*)d_out;

    char* ws = (char*)d_ws;
    int*    counts  = (int*)ws;                         // 3 ints (pad to 256)
    float2* murs    = (float2*)(ws + 256);              // 32768 * 8 B
    int*    rowlist = (int*)(ws + 256 + NB * 8);        // 3 * 32768 * 4 B

    hipMemsetAsync(counts, 0, 16, stream);
    selector_kernel<<<NB / 64, 256, 0, stream>>>(x, gum, w1, b1, w2, b2,
                                                 murs, counts, rowlist);
    head_kernel<<<dim3((NC + 63) / 64, NB / 64, NE), 256, 0, stream>>>(
        x, murs, gamma, beta, hw, hb, counts, rowlist, out);
}

// Round 2
// 750.238 us; speedup vs baseline: 1.0777x; 1.0777x over previous
//
#include <hip/hip_runtime.h>
#include <math.h>

#define NB 32768
#define ND 768
#define NC 474
#define NE 3
#define NH 128
#define GAP_THR 1e-3f

// ---------------------------------------------------------------------------
// Kernel 1: fused selector MLP (fp32) + top-2 gap cascade + LN stats
// Block: 256 threads, 64 rows per block. Ambiguous rows -> redo list.
// ---------------------------------------------------------------------------
__global__ __launch_bounds__(256) void selector_kernel(
    const float* __restrict__ x, const float* __restrict__ gum,
    const float* __restrict__ w1, const float* __restrict__ b1,
    const float* __restrict__ w2, const float* __restrict__ b2,
    float2* __restrict__ murs, int* __restrict__ counts,
    int* __restrict__ rowlist, int* __restrict__ redolist)
{
    const int row0 = blockIdx.x * 64;
    const int t = threadIdx.x;
    const int tx = t & 31;          // col group: cols tx*4 .. tx*4+3 (of 128)
    const int ty = t >> 5;          // row group: rows ty*8 .. ty*8+7 (of 64)

    __shared__ float Xs[16][72];    // [k][row], padded so float4 row-reads align
    __shared__ float Ws[16 * 128];
    __shared__ float logits_s[64][3];

    float acc[8][4];
    #pragma unroll
    for (int r = 0; r < 8; ++r)
        #pragma unroll
        for (int j = 0; j < 4; ++j) acc[r][j] = 0.f;

    const int li = t >> 2;          // row 0..63 for A-tile load
    const int lk = (t & 3) << 2;    // k offset 0..12

    for (int k0 = 0; k0 < ND; k0 += 16) {
        const float4 av = *(const float4*)(x + (size_t)(row0 + li) * ND + k0 + lk);
        Xs[lk + 0][li] = av.x;
        Xs[lk + 1][li] = av.y;
        Xs[lk + 2][li] = av.z;
        Xs[lk + 3][li] = av.w;
        const float4* wsrc = (const float4*)(w1 + (size_t)k0 * NH);
        ((float4*)Ws)[t] = wsrc[t];
        ((float4*)Ws)[t + 256] = wsrc[t + 256];
        __syncthreads();
        #pragma unroll
        for (int kk = 0; kk < 16; ++kk) {
            const float4 a0 = *(const float4*)&Xs[kk][ty * 8];
            const float4 a1 = *(const float4*)&Xs[kk][ty * 8 + 4];
            const float4 b4 = *(const float4*)&Ws[kk * 128 + tx * 4];
            const float ar[8] = {a0.x, a0.y, a0.z, a0.w, a1.x, a1.y, a1.z, a1.w};
            #pragma unroll
            for (int r = 0; r < 8; ++r) {
                acc[r][0] = fmaf(ar[r], b4.x, acc[r][0]);
                acc[r][1] = fmaf(ar[r], b4.y, acc[r][1]);
                acc[r][2] = fmaf(ar[r], b4.z, acc[r][2]);
                acc[r][3] = fmaf(ar[r], b4.w, acc[r][3]);
            }
        }
        __syncthreads();
    }

    // logits partials: relu(h + b1) @ W2 (fp32)
    float part[8][3];
    #pragma unroll
    for (int r = 0; r < 8; ++r) { part[r][0] = 0.f; part[r][1] = 0.f; part[r][2] = 0.f; }
    #pragma unroll
    for (int j = 0; j < 4; ++j) {
        const int c = tx * 4 + j;
        const float bb  = b1[c];
        const float w0  = w2[c * 3 + 0];
        const float wq1 = w2[c * 3 + 1];
        const float wq2 = w2[c * 3 + 2];
        #pragma unroll
        for (int r = 0; r < 8; ++r) {
            float h = acc[r][j] + bb;
            h = fmaxf(h, 0.f);
            part[r][0] = fmaf(h, w0,  part[r][0]);
            part[r][1] = fmaf(h, wq1, part[r][1]);
            part[r][2] = fmaf(h, wq2, part[r][2]);
        }
    }
    #pragma unroll
    for (int m = 16; m >= 1; m >>= 1) {
        #pragma unroll
        for (int r = 0; r < 8; ++r) {
            part[r][0] += __shfl_xor(part[r][0], m);
            part[r][1] += __shfl_xor(part[r][1], m);
            part[r][2] += __shfl_xor(part[r][2], m);
        }
    }
    if (tx == 0) {
        #pragma unroll
        for (int r = 0; r < 8; ++r) {
            logits_s[ty * 8 + r][0] = part[r][0];
            logits_s[ty * 8 + r][1] = part[r][1];
            logits_s[ty * 8 + r][2] = part[r][2];
        }
    }
    __syncthreads();

    // LN stats: 4 threads per row, 192 contiguous elems each
    {
        const int r = t >> 2, q = t & 3;
        const float4* xp = (const float4*)(x + (size_t)(row0 + r) * ND + q * 192);
        float s1 = 0.f, s2 = 0.f;
        #pragma unroll 4
        for (int i = 0; i < 48; ++i) {
            const float4 v = xp[i];
            s1 += v.x + v.y + v.z + v.w;
            s2 += v.x * v.x + v.y * v.y + v.z * v.z + v.w * v.w;
        }
        s1 += __shfl_xor(s1, 1); s2 += __shfl_xor(s2, 1);
        s1 += __shfl_xor(s1, 2); s2 += __shfl_xor(s2, 2);
        if (q == 0) {
            const float mu = s1 * (1.0f / 768.0f);
            const float var = s2 * (1.0f / 768.0f) - mu * mu;
            const float rs = 1.0f / sqrtf(var + 1e-5f);
            murs[row0 + r] = make_float2(mu, rs);
        }
    }

    // argmax with top-2 gap cascade
    if (t < 64) {
        const int grow = row0 + t;
        const float z0 = logits_s[t][0] + b2[0] + gum[grow * 3 + 0];
        const float z1 = logits_s[t][1] + b2[1] + gum[grow * 3 + 1];
        const float z2 = logits_s[t][2] + b2[2] + gum[grow * 3 + 2];
        int be = 0; float best = z0;
        if (z1 > best) { best = z1; be = 1; }
        if (z2 > best) { best = z2; be = 2; }
        float second;
        if (be == 0)      second = fmaxf(z1, z2);
        else if (be == 1) second = fmaxf(z0, z2);
        else              second = fmaxf(z0, z1);
        if (best - second < GAP_THR) {
            const int pos = atomicAdd(&counts[3], 1);
            redolist[pos] = grow;
        } else {
            const int pos = atomicAdd(&counts[be], 1);
            rowlist[be * NB + pos] = grow;
        }
    }
}

// ---------------------------------------------------------------------------
// Kernel 1b: fp64 redo for ambiguous rows (expected ~10-50 rows)
// ---------------------------------------------------------------------------
__global__ __launch_bounds__(128) void redo_kernel(
    const float* __restrict__ x, const float* __restrict__ gum,
    const float* __restrict__ w1, const float* __restrict__ b1,
    const float* __restrict__ w2, const float* __restrict__ b2,
    int* __restrict__ counts, int* __restrict__ rowlist,
    const int* __restrict__ redolist)
{
    const int t = threadIdx.x;
    const int n = counts[3];
    __shared__ double red[2][3];
    for (int i = blockIdx.x; i < n; i += gridDim.x) {
        const int row = redolist[i];
        const float* xr = x + (size_t)row * ND;
        double h = 0.0;
        for (int k = 0; k < ND; ++k)
            h = fma((double)xr[k], (double)w1[(size_t)k * NH + t], h);
        h += (double)b1[t];
        h = h > 0.0 ? h : 0.0;
        double p0 = h * (double)w2[t * 3 + 0];
        double p1 = h * (double)w2[t * 3 + 1];
        double p2 = h * (double)w2[t * 3 + 2];
        #pragma unroll
        for (int m = 32; m >= 1; m >>= 1) {
            p0 += __shfl_xor(p0, m);
            p1 += __shfl_xor(p1, m);
            p2 += __shfl_xor(p2, m);
        }
        if ((t & 63) == 0) {
            red[t >> 6][0] = p0; red[t >> 6][1] = p1; red[t >> 6][2] = p2;
        }
        __syncthreads();
        if (t == 0) {
            double best = 0.0; int be = 0;
            #pragma unroll
            for (int e = 0; e < NE; ++e) {
                const double z = red[0][e] + red[1][e] + (double)b2[e]
                               + (double)gum[(size_t)row * 3 + e];
                if (e == 0 || z > best) { best = z; be = e; }
            }
            const int pos = atomicAdd(&counts[be], 1);
            rowlist[be * NB + pos] = row;
        }
        __syncthreads();
    }
}

// ---------------------------------------------------------------------------
// Kernel 2: grouped head GEMM. out[row] = (LN(x[row])*gamma[e]+beta[e]) @ hw[e] + hb[e]
// ---------------------------------------------------------------------------
__global__ __launch_bounds__(256) void head_kernel(
    const float* __restrict__ x, const float2* __restrict__ murs,
    const float* __restrict__ gamma, const float* __restrict__ beta,
    const float* __restrict__ hw, const float* __restrict__ hb,
    const int* __restrict__ counts, const int* __restrict__ rowlist,
    float* __restrict__ out)
{
    const int e = blockIdx.z;
    const int cnt = counts[e];
    const int rc0 = blockIdx.y * 64;
    if (rc0 >= cnt) return;
    const int c0 = blockIdx.x * 64;
    const int t = threadIdx.x;
    const int tx = t & 15;
    const int ty = t >> 4;

    __shared__ float As[16][65];
    __shared__ float Bs[16][68];

    float acc[4][4] = {};

    const int ai = t >> 2;
    const int ak = (t & 3) << 2;
    const int ridx = rc0 + ai;
    const bool av = ridx < cnt;
    int arow = 0; float mu = 0.f, rs = 0.f;
    if (av) {
        arow = rowlist[e * NB + ridx];
        const float2 mr = murs[arow];
        mu = mr.x; rs = mr.y;
    }
    const float* xrow = x + (size_t)arow * ND;
    const float* gmp = gamma + e * ND;
    const float* btp = beta + e * ND;

    const int bk = t >> 4;
    const int bc = (t & 15) << 2;
    const float* hwe = hw + (size_t)e * ND * NC;

    for (int k0 = 0; k0 < ND; k0 += 16) {
        float4 xv = make_float4(0.f, 0.f, 0.f, 0.f);
        if (av) xv = *(const float4*)(xrow + k0 + ak);
        const float4 gv = *(const float4*)(gmp + k0 + ak);
        const float4 bv = *(const float4*)(btp + k0 + ak);
        As[ak + 0][ai] = av ? ((xv.x - mu) * rs * gv.x + bv.x) : 0.f;
        As[ak + 1][ai] = av ? ((xv.y - mu) * rs * gv.y + bv.y) : 0.f;
        As[ak + 2][ai] = av ? ((xv.z - mu) * rs * gv.z + bv.z) : 0.f;
        As[ak + 3][ai] = av ? ((xv.w - mu) * rs * gv.w + bv.w) : 0.f;

        const int c = c0 + bc;
        const float* bsrc = hwe + (size_t)(k0 + bk) * NC + c;
        float2 p0 = make_float2(0.f, 0.f), p1 = make_float2(0.f, 0.f);
        if (c < NC) p0 = *(const float2*)bsrc;
        if (c + 2 < NC) p1 = *(const float2*)(bsrc + 2);
        Bs[bk][bc + 0] = p0.x; Bs[bk][bc + 1] = p0.y;
        Bs[bk][bc + 2] = p1.x; Bs[bk][bc + 3] = p1.y;
        __syncthreads();
        #pragma unroll
        for (int kk = 0; kk < 16; ++kk) {
            const float4 b4 = *(const float4*)&Bs[kk][tx * 4];
            #pragma unroll
            for (int r = 0; r < 4; ++r) {
                const float a = As[kk][ty * 4 + r];
                acc[r][0] = fmaf(a, b4.x, acc[r][0]);
                acc[r][1] = fmaf(a, b4.y, acc[r][1]);
                acc[r][2] = fmaf(a, b4.z, acc[r][2]);
                acc[r][3] = fmaf(a, b4.w, acc[r][3]);
            }
        }
        __syncthreads();
    }

    #pragma unroll
    for (int r = 0; r < 4; ++r) {
        const int ridx2 = rc0 + ty * 4 + r;
        if (ridx2 >= cnt) continue;
        const int orow = rowlist[e * NB + ridx2];
        float* op = out + (size_t)orow * NC;
        #pragma unroll
        for (int j = 0; j < 4; ++j) {
            const int c = c0 + tx * 4 + j;
            if (c < NC) op[c] = acc[r][j] + hb[e * NC + c];
        }
    }
}

extern "C" void kernel_launch(void* const* d_in, const int* in_sizes, int n_in,
                              void* d_out, int out_size, void* d_ws, size_t ws_size,
                              hipStream_t stream) {
    const float* x     = (const float*)d_in[0];
    const float* gum   = (const float*)d_in[1];
    const float* w1    = (const float*)d_in[2];
    const float* b1    = (const float*)d_in[3];
    const float* w2    = (const float*)d_in[4];
    const float* b2    = (const float*)d_in[5];
    const float* gamma = (const float*)d_in[6];
    const float* beta  = (const float*)d_in[7];
    const float* hw    = (const float*)d_in[8];
    const float* hb    = (const float*)d_in[9];
    float* out = (float*)d_out;

    char* ws = (char*)d_ws;
    int*    counts   = (int*)ws;                         // [0..2]=buckets, [3]=redo
    float2* murs     = (float2*)(ws + 256);              // NB * 8 B
    int*    rowlist  = (int*)(ws + 256 + NB * 8);        // 3 * NB * 4 B
    int*    redolist = (int*)(ws + 256 + NB * 8 + 3 * NB * 4); // NB * 4 B

    hipMemsetAsync(counts, 0, 16, stream);
    selector_kernel<<<NB / 64, 256, 0, stream>>>(x, gum, w1, b1, w2, b2,
                                                 murs, counts, rowlist, redolist);
    redo_kernel<<<128, 128, 0, stream>>>(x, gum, w1, b1, w2, b2,
                                         counts, rowlist, redolist);
    head_kernel<<<dim3((NC + 63) / 64, NB / 64, NE), 256, 0, stream>>>(
        x, murs, gamma, beta, hw, hb, counts, rowlist, out);
}

// Round 3
// 656.012 us; speedup vs baseline: 1.2325x; 1.1436x over previous
//
#include <hip/hip_runtime.h>
#include <hip/hip_bf16.h>
#include <math.h>

#define NB 32768
#define ND 768
#define NC 474
#define NCP 512
#define NE 3
#define NH 128
#define GAP_THR 0.06f

typedef short v8s __attribute__((ext_vector_type(8)));
typedef float v4f __attribute__((ext_vector_type(4)));

#define GLD16(gp, lp) __builtin_amdgcn_global_load_lds( \
    (const __attribute__((address_space(1))) void*)(gp), \
    (__attribute__((address_space(3))) void*)(lp), 16, 0, 0)

static __device__ __forceinline__ short f2bf(float f) {
    __hip_bfloat16 h = __float2bfloat16(f);
    return *reinterpret_cast<short*>(&h);
}

// ---------------------------------------------------------------------------
// prep: hwbT[e][c][k] = bf16(gamma[e][k]*hw[e][k][c]) transposed + slot-swizzled;
//       w1bT[c][k]    = bf16(w1[k][c]) same layout.
// Swizzle: within each 32-k (64B) group, 16B slot s -> s ^ ((c>>1)&3).
// ---------------------------------------------------------------------------
__global__ __launch_bounds__(256) void prep_kernel(
    const float* __restrict__ hw, const float* __restrict__ gamma,
    const float* __restrict__ w1,
    short* __restrict__ hwbT, short* __restrict__ w1bT)
{
    __shared__ float T[32][72];
    const int t = threadIdx.x;
    const int id = blockIdx.x;
    const float* src; short* dst; int stride, ncs; int e = 0, cc, kc;
    bool is_exp = (id < 576);
    if (is_exp) {
        e = id / 192; const int r2 = id % 192; cc = r2 / 24; kc = r2 % 24;
        src = hw + (size_t)e * ND * NC; stride = NC; ncs = NC;
        dst = hwbT + (size_t)e * NCP * ND;
    } else {
        const int j = id - 576; cc = j / 24; kc = j % 24;
        src = w1; stride = NH; ncs = NH; dst = w1bT;
    }
    const int c0 = cc * 64, k0 = kc * 32;
    {
        const int kl = t >> 3, c8 = (t & 7) * 8;
        const float g = is_exp ? gamma[e * ND + k0 + kl] : 1.f;
        #pragma unroll
        for (int j = 0; j < 8; ++j) {
            const int cg = c0 + c8 + j;
            const float v = (cg < ncs) ? src[(size_t)(k0 + kl) * stride + cg] : 0.f;
            T[kl][c8 + j] = v * g;
        }
    }
    __syncthreads();
    {
        const int cl = t >> 2, q = t & 3;
        const int cg = c0 + cl;
        const int sp = q ^ ((cg >> 1) & 3);
        union { short s[8]; int4 v; } u;
        #pragma unroll
        for (int j = 0; j < 8; ++j) u.s[j] = f2bf(T[q * 8 + j][cl]);
        *(int4*)(dst + (size_t)cg * ND + k0 + sp * 8) = u.v;
    }
}

// hbias[e][c] = hb[e][c] + sum_k beta[e][k]*hw[e][k][c]
__global__ __launch_bounds__(256) void bias_kernel(
    const float* __restrict__ hw, const float* __restrict__ beta,
    const float* __restrict__ hb, float* __restrict__ hbias)
{
    const int e = blockIdx.x, t = threadIdx.x;
    float a0 = 0.f, a1 = 0.f;
    const float* he = hw + (size_t)e * ND * NC;
    const int c1 = t + 256;
    for (int k = 0; k < ND; ++k) {
        const float b = beta[e * ND + k];
        const float* row = he + (size_t)k * NC;
        a0 = fmaf(b, row[t], a0);
        if (c1 < NC) a1 = fmaf(b, row[c1], a1);
    }
    hbias[e * NCP + t] = hb[e * NC + t] + a0;
    if (c1 < NC) hbias[e * NCP + c1] = hb[e * NC + c1] + a1;
}

// ---------------------------------------------------------------------------
// selector: 64 rows/block, bf16 MFMA X@W1, in-register logits, LN stats,
// gap cascade -> buckets / redo list.
// ---------------------------------------------------------------------------
__global__ __launch_bounds__(256, 4) void selector_kernel(
    const float* __restrict__ x, const float* __restrict__ gum,
    const short* __restrict__ w1bT, const float* __restrict__ b1,
    const float* __restrict__ w2, const float* __restrict__ b2,
    float2* __restrict__ murs, int* __restrict__ counts,
    int* __restrict__ rowlist, int* __restrict__ redolist)
{
    __shared__ __align__(16) short As[64 * 40];   // stride 80B (padded, conflict-free)
    __shared__ __align__(16) short Bs[128 * 32];  // [c][32k] swizzled slots
    __shared__ float b1s[NH];
    __shared__ float w2s[NH * 3];

    const int t = threadIdx.x;
    const int row0 = blockIdx.x * 64;
    const int w = t >> 6, l = t & 63;

    if (t < NH) {
        b1s[t] = b1[t];
        w2s[t*3+0] = w2[t*3+0]; w2s[t*3+1] = w2[t*3+1]; w2s[t*3+2] = w2[t*3+2];
    }

    v4f acc[8];
    #pragma unroll
    for (int i = 0; i < 8; ++i) acc[i] = (v4f)(0.f);

    const int sr = t >> 2;          // staging row 0..63
    const int sq = t & 3;           // k-oct within 32-window
    const float* xrow = x + (size_t)(row0 + sr) * ND + sq * 8;
    float s1 = 0.f, s2 = 0.f;

    for (int k0 = 0; k0 < ND; k0 += 32) {
        const float4 v0 = *(const float4*)(xrow + k0);
        const float4 v1 = *(const float4*)(xrow + k0 + 4);
        s1 += v0.x+v0.y+v0.z+v0.w + v1.x+v1.y+v1.z+v1.w;
        s2 += v0.x*v0.x+v0.y*v0.y+v0.z*v0.z+v0.w*v0.w
            + v1.x*v1.x+v1.y*v1.y+v1.z*v1.z+v1.w*v1.w;
        v8s av;
        av[0]=f2bf(v0.x); av[1]=f2bf(v0.y); av[2]=f2bf(v0.z); av[3]=f2bf(v0.w);
        av[4]=f2bf(v1.x); av[5]=f2bf(v1.y); av[6]=f2bf(v1.z); av[7]=f2bf(v1.w);
        *(v8s*)&As[sr * 40 + sq * 8] = av;
        #pragma unroll
        for (int i = 0; i < 2; ++i) {
            const int cRow = w * 32 + i * 16 + (l >> 2);
            GLD16(w1bT + (size_t)cRow * ND + k0 + (l & 3) * 8,
                  &Bs[(w * 32 + i * 16) * 32]);
        }
        __syncthreads();
        {
            const int g = l >> 4, lm = l & 15;
            const v8s a = *(const v8s*)&As[(w * 16 + lm) * 40 + g * 8];
            #pragma unroll
            for (int nf = 0; nf < 8; ++nf) {
                const int c = nf * 16 + lm;
                const v8s b = *(const v8s*)&Bs[c * 32 + (g ^ ((c >> 1) & 3)) * 8];
                acc[nf] = __builtin_amdgcn_mfma_f32_16x16x32_bf16(a, b, acc[nf], 0, 0, 0);
            }
        }
        __syncthreads();
    }

    // LN stats: row sr split over 4 threads (sq)
    {
        float r1 = s1 + __shfl_xor(s1, 1);
        float r2 = s2 + __shfl_xor(s2, 1);
        r1 += __shfl_xor(r1, 2);
        r2 += __shfl_xor(r2, 2);
        if (sq == 0) {
            const float mu = r1 * (1.f/768.f);
            const float var = r2 * (1.f/768.f) - mu*mu;
            const float rsq = rsqrtf(var + 1e-5f);
            murs[row0 + sr] = make_float2(mu, rsq);
        }
    }

    // logits = relu(h + b1) @ w2, reduced across the 16 col-lanes
    const int g4 = l >> 4, lm = l & 15;
    float p[4][3];
    #pragma unroll
    for (int r = 0; r < 4; ++r) { p[r][0]=0.f; p[r][1]=0.f; p[r][2]=0.f; }
    #pragma unroll
    for (int nf = 0; nf < 8; ++nf) {
        const int c = nf * 16 + lm;
        const float bb = b1s[c];
        const float wa = w2s[c*3], wb = w2s[c*3+1], wcc = w2s[c*3+2];
        #pragma unroll
        for (int r = 0; r < 4; ++r) {
            const float h = fmaxf(acc[nf][r] + bb, 0.f);
            p[r][0] = fmaf(h, wa,  p[r][0]);
            p[r][1] = fmaf(h, wb,  p[r][1]);
            p[r][2] = fmaf(h, wcc, p[r][2]);
        }
    }
    #pragma unroll
    for (int m = 1; m < 16; m <<= 1) {
        #pragma unroll
        for (int r = 0; r < 4; ++r) {
            p[r][0] += __shfl_xor(p[r][0], m);
            p[r][1] += __shfl_xor(p[r][1], m);
            p[r][2] += __shfl_xor(p[r][2], m);
        }
    }
    if (lm == 0) {
        const float bb0 = b2[0], bb1 = b2[1], bb2 = b2[2];
        #pragma unroll
        for (int r = 0; r < 4; ++r) {
            const int grow = row0 + w * 16 + g4 * 4 + r;
            const float z0 = p[r][0] + bb0 + gum[grow*3+0];
            const float z1 = p[r][1] + bb1 + gum[grow*3+1];
            const float z2 = p[r][2] + bb2 + gum[grow*3+2];
            int be = 0; float best = z0;
            if (z1 > best) { best = z1; be = 1; }
            if (z2 > best) { best = z2; be = 2; }
            const float second = (be==0) ? fmaxf(z1,z2) : (be==1) ? fmaxf(z0,z2) : fmaxf(z0,z1);
            if (best - second < GAP_THR) {
                const int pos = atomicAdd(&counts[3], 1);
                redolist[pos] = grow;
            } else {
                const int pos = atomicAdd(&counts[be], 1);
                rowlist[be * NB + pos] = grow;
            }
        }
    }
}

// fp64 redo for ambiguous rows
__global__ __launch_bounds__(128) void redo_kernel(
    const float* __restrict__ x, const float* __restrict__ gum,
    const float* __restrict__ w1, const float* __restrict__ b1,
    const float* __restrict__ w2, const float* __restrict__ b2,
    int* __restrict__ counts, int* __restrict__ rowlist,
    const int* __restrict__ redolist)
{
    const int t = threadIdx.x;
    const int n = counts[3];
    __shared__ double red[2][3];
    for (int i = blockIdx.x; i < n; i += gridDim.x) {
        const int row = redolist[i];
        const float* xr = x + (size_t)row * ND;
        double h = 0.0;
        for (int k = 0; k < ND; ++k)
            h = fma((double)xr[k], (double)w1[(size_t)k * NH + t], h);
        h += (double)b1[t];
        h = h > 0.0 ? h : 0.0;
        double p0 = h * (double)w2[t * 3 + 0];
        double p1 = h * (double)w2[t * 3 + 1];
        double p2 = h * (double)w2[t * 3 + 2];
        #pragma unroll
        for (int m = 32; m >= 1; m >>= 1) {
            p0 += __shfl_xor(p0, m);
            p1 += __shfl_xor(p1, m);
            p2 += __shfl_xor(p2, m);
        }
        if ((t & 63) == 0) {
            red[t >> 6][0] = p0; red[t >> 6][1] = p1; red[t >> 6][2] = p2;
        }
        __syncthreads();
        if (t == 0) {
            double best = 0.0; int be = 0;
            #pragma unroll
            for (int e = 0; e < NE; ++e) {
                const double z = red[0][e] + red[1][e] + (double)b2[e]
                               + (double)gum[(size_t)row * 3 + e];
                if (e == 0 || z > best) { best = z; be = e; }
            }
            const int pos = atomicAdd(&counts[be], 1);
            rowlist[be * NB + pos] = row;
        }
        __syncthreads();
    }
}

// ---------------------------------------------------------------------------
// head: grouped bf16 MFMA GEMM, BM=128 x BN=256, K=768 (BK=32).
// ---------------------------------------------------------------------------
__global__ __launch_bounds__(256, 2) void head_kernel(
    const float* __restrict__ x, const float2* __restrict__ murs,
    const short* __restrict__ hwbT, const float* __restrict__ hbias,
    const int* __restrict__ counts, const int* __restrict__ rowlist,
    float* __restrict__ out)
{
    const int e = blockIdx.z;
    const int cnt = counts[e];
    const int rc0 = blockIdx.y * 128;
    if (rc0 >= cnt) return;
    const int c0 = blockIdx.x * 256;

    __shared__ __align__(16) short As[128 * 40];
    __shared__ __align__(16) short Bs[256 * 32];
    __shared__ float hbs[256];
    __shared__ int rows_s[128];

    const int t = threadIdx.x;
    const int w = t >> 6, l = t & 63;
    const int wr = w >> 1, wc = w & 1;

    const int sr = t >> 1;
    const int sh = (t & 1) * 16;
    const int ridx = rc0 + sr;
    const bool av = ridx < cnt;
    const int arow = av ? rowlist[e * NB + ridx] : 0;
    float mu = 0.f, rs = 0.f;
    if (av) { const float2 mr = murs[arow]; mu = mr.x; rs = mr.y; }
    const float nm = -mu * rs;
    const float* xrow = x + (size_t)arow * ND + sh;

    if (t < 128) {
        const int ri = rc0 + t;
        rows_s[t] = (ri < cnt) ? rowlist[e * NB + ri] : -1;
    }
    hbs[t] = (c0 + t < NC) ? hbias[e * NCP + c0 + t] : 0.f;
    const short* hwe = hwbT + (size_t)e * NCP * ND;

    v4f acc[4][8];
    #pragma unroll
    for (int i = 0; i < 4; ++i)
        #pragma unroll
        for (int j = 0; j < 8; ++j) acc[i][j] = (v4f)(0.f);

    for (int k0 = 0; k0 < ND; k0 += 32) {
        float4 v0, v1, v2, v3;
        if (av) {
            v0 = *(const float4*)(xrow + k0);
            v1 = *(const float4*)(xrow + k0 + 4);
            v2 = *(const float4*)(xrow + k0 + 8);
            v3 = *(const float4*)(xrow + k0 + 12);
        } else {
            v0 = v1 = v2 = v3 = make_float4(0.f, 0.f, 0.f, 0.f);
        }
        v8s a0, a1;
        a0[0]=f2bf(fmaf(v0.x,rs,nm)); a0[1]=f2bf(fmaf(v0.y,rs,nm));
        a0[2]=f2bf(fmaf(v0.z,rs,nm)); a0[3]=f2bf(fmaf(v0.w,rs,nm));
        a0[4]=f2bf(fmaf(v1.x,rs,nm)); a0[5]=f2bf(fmaf(v1.y,rs,nm));
        a0[6]=f2bf(fmaf(v1.z,rs,nm)); a0[7]=f2bf(fmaf(v1.w,rs,nm));
        a1[0]=f2bf(fmaf(v2.x,rs,nm)); a1[1]=f2bf(fmaf(v2.y,rs,nm));
        a1[2]=f2bf(fmaf(v2.z,rs,nm)); a1[3]=f2bf(fmaf(v2.w,rs,nm));
        a1[4]=f2bf(fmaf(v3.x,rs,nm)); a1[5]=f2bf(fmaf(v3.y,rs,nm));
        a1[6]=f2bf(fmaf(v3.z,rs,nm)); a1[7]=f2bf(fmaf(v3.w,rs,nm));
        const int s0 = (t & 1) * 2;
        *(v8s*)&As[sr * 40 + s0 * 8] = a0;
        *(v8s*)&As[sr * 40 + (s0 + 1) * 8] = a1;
        #pragma unroll
        for (int i = 0; i < 4; ++i) {
            const int cRow = w * 64 + i * 16 + (l >> 2);
            GLD16(hwe + (size_t)(c0 + cRow) * ND + k0 + (l & 3) * 8,
                  &Bs[(w * 64 + i * 16) * 32]);
        }
        __syncthreads();
        {
            const int g = l >> 4, lm = l & 15;
            v8s af[4], bfr[8];
            #pragma unroll
            for (int mf = 0; mf < 4; ++mf)
                af[mf] = *(const v8s*)&As[(wr*64 + mf*16 + lm) * 40 + g * 8];
            #pragma unroll
            for (int nf = 0; nf < 8; ++nf) {
                const int c = wc*128 + nf*16 + lm;
                bfr[nf] = *(const v8s*)&Bs[c * 32 + (g ^ ((c >> 1) & 3)) * 8];
            }
            #pragma unroll
            for (int mf = 0; mf < 4; ++mf)
                #pragma unroll
                for (int nf = 0; nf < 8; ++nf)
                    acc[mf][nf] = __builtin_amdgcn_mfma_f32_16x16x32_bf16(
                        af[mf], bfr[nf], acc[mf][nf], 0, 0, 0);
        }
        __syncthreads();
    }

    const int g = l >> 4, lm = l & 15;
    #pragma unroll
    for (int mf = 0; mf < 4; ++mf) {
        #pragma unroll
        for (int r = 0; r < 4; ++r) {
            const int rl = wr*64 + mf*16 + g*4 + r;
            const int orow = rows_s[rl];
            if (orow < 0) continue;
            float* op = out + (size_t)orow * NC;
            #pragma unroll
            for (int nf = 0; nf < 8; ++nf) {
                const int cl = wc*128 + nf*16 + lm;
                const int c = c0 + cl;
                if (c < NC) op[c] = acc[mf][nf][r] + hbs[cl];
            }
        }
    }
}

extern "C" void kernel_launch(void* const* d_in, const int* in_sizes, int n_in,
                              void* d_out, int out_size, void* d_ws, size_t ws_size,
                              hipStream_t stream) {
    const float* x     = (const float*)d_in[0];
    const float* gum   = (const float*)d_in[1];
    const float* w1    = (const float*)d_in[2];
    const float* b1    = (const float*)d_in[3];
    const float* w2    = (const float*)d_in[4];
    const float* b2    = (const float*)d_in[5];
    const float* gamma = (const float*)d_in[6];
    const float* beta  = (const float*)d_in[7];
    const float* hw    = (const float*)d_in[8];
    const float* hb    = (const float*)d_in[9];
    float* out = (float*)d_out;

    char* ws = (char*)d_ws;
    int*    counts   = (int*)ws;                            // 16 B (zeroed)
    float2* murs     = (float2*)(ws + 256);                 // 256 KiB
    int*    rowlist  = (int*)(ws + 262400);                 // 384 KiB
    int*    redolist = (int*)(ws + 655616);                 // 128 KiB
    float*  hbias    = (float*)(ws + 786688);               // 6 KiB
    short*  w1bT     = (short*)(ws + 792832);               // 192 KiB
    short*  hwbT     = (short*)(ws + 989440);               // 2.25 MiB

    hipMemsetAsync(counts, 0, 16, stream);
    prep_kernel<<<624, 256, 0, stream>>>(hw, gamma, w1, hwbT, w1bT);
    bias_kernel<<<3, 256, 0, stream>>>(hw, beta, hb, hbias);
    selector_kernel<<<NB / 64, 256, 0, stream>>>(x, gum, w1bT, b1, w2, b2,
                                                 murs, counts, rowlist, redolist);
    redo_kernel<<<512, 128, 0, stream>>>(x, gum, w1, b1, w2, b2,
                                         counts, rowlist, redolist);
    head_kernel<<<dim3(2, NB / 128, 3), 256, 0, stream>>>(
        x, murs, hwbT, hbias, counts, rowlist, out);
}

// Round 4
// 531.894 us; speedup vs baseline: 1.5201x; 1.2334x over previous
//
#include <hip/hip_runtime.h>
#include <hip/hip_bf16.h>
#include <math.h>

#define NB 32768
#define ND 768
#define NC 474
#define NCP 512
#define NE 3
#define NH 128
#define GAP_THR 0.06f

typedef short v8s __attribute__((ext_vector_type(8)));
typedef float v4f __attribute__((ext_vector_type(4)));

#define GLD16(gp, lp) __builtin_amdgcn_global_load_lds( \
    (const __attribute__((address_space(1))) void*)(gp), \
    (__attribute__((address_space(3))) void*)(lp), 16, 0, 0)

static __device__ __forceinline__ short f2bf(float f) {
    __hip_bfloat16 h = __float2bfloat16(f);
    return *reinterpret_cast<short*>(&h);
}

// ---------------------------------------------------------------------------
// prep: hwbT[e][c][k] = bf16(gamma[e][k]*hw[e][k][c]) transposed + slot-swizzled;
//       w1bT[c][k]    = bf16(w1[k][c]) same layout.
// Swizzle: within each 32-k (64B) group, 16B slot s -> s ^ ((c>>1)&3).
// ---------------------------------------------------------------------------
__global__ __launch_bounds__(256) void prep_kernel(
    const float* __restrict__ hw, const float* __restrict__ gamma,
    const float* __restrict__ w1,
    short* __restrict__ hwbT, short* __restrict__ w1bT)
{
    __shared__ float T[32][72];
    const int t = threadIdx.x;
    const int id = blockIdx.x;
    const float* src; short* dst; int stride, ncs; int e = 0, cc, kc;
    bool is_exp = (id < 576);
    if (is_exp) {
        e = id / 192; const int r2 = id % 192; cc = r2 / 24; kc = r2 % 24;
        src = hw + (size_t)e * ND * NC; stride = NC; ncs = NC;
        dst = hwbT + (size_t)e * NCP * ND;
    } else {
        const int j = id - 576; cc = j / 24; kc = j % 24;
        src = w1; stride = NH; ncs = NH; dst = w1bT;
    }
    const int c0 = cc * 64, k0 = kc * 32;
    {
        const int kl = t >> 3, c8 = (t & 7) * 8;
        const float g = is_exp ? gamma[e * ND + k0 + kl] : 1.f;
        #pragma unroll
        for (int j = 0; j < 8; ++j) {
            const int cg = c0 + c8 + j;
            const float v = (cg < ncs) ? src[(size_t)(k0 + kl) * stride + cg] : 0.f;
            T[kl][c8 + j] = v * g;
        }
    }
    __syncthreads();
    {
        const int cl = t >> 2, q = t & 3;
        const int cg = c0 + cl;
        const int sp = q ^ ((cg >> 1) & 3);
        union { short s[8]; int4 v; } u;
        #pragma unroll
        for (int j = 0; j < 8; ++j) u.s[j] = f2bf(T[q * 8 + j][cl]);
        *(int4*)(dst + (size_t)cg * ND + k0 + sp * 8) = u.v;
    }
}

// bias partials: bpart[e][kc][c] = sum_{k in chunk} beta[e][k]*hw[e][k][c]
__global__ __launch_bounds__(256) void bias_part_kernel(
    const float* __restrict__ hw, const float* __restrict__ beta,
    float* __restrict__ bpart)
{
    const int e = blockIdx.x, kc = blockIdx.y, t = threadIdx.x;
    const float* he = hw + (size_t)e * ND * NC;
    float a0 = 0.f, a1 = 0.f;
    const int c1 = t + 256;
    for (int k = kc * 48; k < kc * 48 + 48; ++k) {
        const float b = beta[e * ND + k];
        const float* row = he + (size_t)k * NC;
        a0 = fmaf(b, row[t], a0);
        if (c1 < NC) a1 = fmaf(b, row[c1], a1);
    }
    float* bp = bpart + (size_t)(e * 16 + kc) * NCP;
    bp[t] = a0;
    bp[c1] = (c1 < NC) ? a1 : 0.f;
}

__global__ __launch_bounds__(256) void bias_comb_kernel(
    const float* __restrict__ bpart, const float* __restrict__ hb,
    float* __restrict__ hbias)
{
    const int e = blockIdx.x, t = threadIdx.x;
    #pragma unroll
    for (int h = 0; h < 2; ++h) {
        const int c = t + h * 256;
        float s = 0.f;
        for (int kc = 0; kc < 16; ++kc)
            s += bpart[(size_t)(e * 16 + kc) * NCP + c];
        hbias[e * NCP + c] = (c < NC) ? hb[e * NC + c] + s : 0.f;
    }
}

// ---------------------------------------------------------------------------
// selector: 64 rows/block. Per K-half: burst-load x (24 float4/thread),
// stage full half-K A-tile once, then 12 double-buffered B steps (GLD16
// prefetch issued before compute). Epilogue: LN stats, logits, gap cascade.
// ---------------------------------------------------------------------------
__global__ __launch_bounds__(256) void selector_kernel(
    const float* __restrict__ x, const float* __restrict__ gum,
    const short* __restrict__ w1bT, const float* __restrict__ b1,
    const float* __restrict__ w2, const float* __restrict__ b2,
    float2* __restrict__ murs, int* __restrict__ counts,
    int* __restrict__ rowlist, int* __restrict__ redolist)
{
    __shared__ __align__(16) short As[64 * 392];   // 64 rows x 384k, stride 392
    __shared__ __align__(16) short Bs[2 * 4096];   // 2 x (128c x 32k)
    __shared__ float b1s[NH];
    __shared__ float w2s[NH * 3];

    const int t = threadIdx.x;
    const int row0 = blockIdx.x * 64;
    const int w = t >> 6, l = t & 63;
    const int g = l >> 4, lm = l & 15;
    const int sr = t >> 2, sq = t & 3;

    if (t < NH) {
        b1s[t] = b1[t];
        w2s[t*3+0] = w2[t*3+0]; w2s[t*3+1] = w2[t*3+1]; w2s[t*3+2] = w2[t*3+2];
    }

    v4f acc[8];
    #pragma unroll
    for (int i = 0; i < 8; ++i) acc[i] = (v4f)(0.f);

    const float* xrow = x + (size_t)(row0 + sr) * ND + sq * 96;
    float s1 = 0.f, s2 = 0.f;
    int cur = 0;

    #pragma unroll 1
    for (int hf = 0; hf < 2; ++hf) {
        const int kh = hf * 384;
        // x burst: this thread's 96 floats of the half
        float4 xv[24];
        #pragma unroll
        for (int i = 0; i < 24; ++i)
            xv[i] = *(const float4*)(xrow + kh + i * 4);
        // prime B tile ks=0 of this half
        #pragma unroll
        for (int i = 0; i < 2; ++i) {
            const int crow = w * 32 + i * 16 + (l >> 2);
            const int off = __builtin_amdgcn_readfirstlane(
                cur * 4096 + (w * 32 + i * 16) * 32);
            GLD16(w1bT + (size_t)crow * ND + kh + (l & 3) * 8, Bs + off);
        }
        __syncthreads();   // prev-half LDS reads done; x + prime drained
        // convert + LN stats + A-tile write
        #pragma unroll
        for (int i = 0; i < 12; ++i) {
            const float4 a = xv[2*i], b = xv[2*i+1];
            s1 += a.x+a.y+a.z+a.w + b.x+b.y+b.z+b.w;
            s2 += a.x*a.x+a.y*a.y+a.z*a.z+a.w*a.w
                + b.x*b.x+b.y*b.y+b.z*b.z+b.w*b.w;
            v8s av;
            av[0]=f2bf(a.x); av[1]=f2bf(a.y); av[2]=f2bf(a.z); av[3]=f2bf(a.w);
            av[4]=f2bf(b.x); av[5]=f2bf(b.y); av[6]=f2bf(b.z); av[7]=f2bf(b.w);
            *(v8s*)&As[sr * 392 + sq * 96 + i * 8] = av;
        }
        __syncthreads();   // A ready, B tile0 landed
        #pragma unroll 1
        for (int ks = 0; ks < 12; ++ks) {
            if (ks < 11) {  // prefetch next B tile before compute
                #pragma unroll
                for (int i = 0; i < 2; ++i) {
                    const int crow = w * 32 + i * 16 + (l >> 2);
                    const int off = __builtin_amdgcn_readfirstlane(
                        (cur ^ 1) * 4096 + (w * 32 + i * 16) * 32);
                    GLD16(w1bT + (size_t)crow * ND + kh + (ks + 1) * 32 + (l & 3) * 8,
                          Bs + off);
                }
            }
            const v8s a = *(const v8s*)&As[(w * 16 + lm) * 392 + ks * 32 + g * 8];
            #pragma unroll
            for (int nf = 0; nf < 8; ++nf) {
                const int c = nf * 16 + lm;
                const v8s bv = *(const v8s*)&Bs[cur * 4096 + c * 32 + (g ^ ((c >> 1) & 3)) * 8];
                acc[nf] = __builtin_amdgcn_mfma_f32_16x16x32_bf16(a, bv, acc[nf], 0, 0, 0);
            }
            __syncthreads();
            cur ^= 1;
        }
    }

    // LN stats: reduce across the 4 threads sharing a row
    {
        float r1 = s1 + __shfl_xor(s1, 1);
        float r2 = s2 + __shfl_xor(s2, 1);
        r1 += __shfl_xor(r1, 2);
        r2 += __shfl_xor(r2, 2);
        if (sq == 0) {
            const float mu = r1 * (1.f/768.f);
            const float var = r2 * (1.f/768.f) - mu * mu;
            murs[row0 + sr] = make_float2(mu, rsqrtf(var + 1e-5f));
        }
    }

    // logits = relu(h + b1) @ w2, reduced across the 16 col-lanes
    float p[4][3];
    #pragma unroll
    for (int r = 0; r < 4; ++r) { p[r][0]=0.f; p[r][1]=0.f; p[r][2]=0.f; }
    #pragma unroll
    for (int nf = 0; nf < 8; ++nf) {
        const int c = nf * 16 + lm;
        const float bb = b1s[c];
        const float wa = w2s[c*3], wb = w2s[c*3+1], wcc = w2s[c*3+2];
        #pragma unroll
        for (int r = 0; r < 4; ++r) {
            const float h = fmaxf(acc[nf][r] + bb, 0.f);
            p[r][0] = fmaf(h, wa,  p[r][0]);
            p[r][1] = fmaf(h, wb,  p[r][1]);
            p[r][2] = fmaf(h, wcc, p[r][2]);
        }
    }
    #pragma unroll
    for (int m = 1; m < 16; m <<= 1) {
        #pragma unroll
        for (int r = 0; r < 4; ++r) {
            p[r][0] += __shfl_xor(p[r][0], m);
            p[r][1] += __shfl_xor(p[r][1], m);
            p[r][2] += __shfl_xor(p[r][2], m);
        }
    }
    if (lm == 0) {
        const float bb0 = b2[0], bb1 = b2[1], bb2 = b2[2];
        #pragma unroll
        for (int r = 0; r < 4; ++r) {
            const int grow = row0 + w * 16 + g * 4 + r;
            const float z0 = p[r][0] + bb0 + gum[grow*3+0];
            const float z1 = p[r][1] + bb1 + gum[grow*3+1];
            const float z2 = p[r][2] + bb2 + gum[grow*3+2];
            int be = 0; float best = z0;
            if (z1 > best) { best = z1; be = 1; }
            if (z2 > best) { best = z2; be = 2; }
            const float second = (be==0) ? fmaxf(z1,z2) : (be==1) ? fmaxf(z0,z2) : fmaxf(z0,z1);
            if (best - second < GAP_THR) {
                const int pos = atomicAdd(&counts[3], 1);
                redolist[pos] = grow;
            } else {
                const int pos = atomicAdd(&counts[be], 1);
                rowlist[be * NB + pos] = grow;
            }
        }
    }
}

// fp64 redo for ambiguous rows
__global__ __launch_bounds__(128) void redo_kernel(
    const float* __restrict__ x, const float* __restrict__ gum,
    const float* __restrict__ w1, const float* __restrict__ b1,
    const float* __restrict__ w2, const float* __restrict__ b2,
    int* __restrict__ counts, int* __restrict__ rowlist,
    const int* __restrict__ redolist)
{
    const int t = threadIdx.x;
    const int n = counts[3];
    __shared__ double red[2][3];
    for (int i = blockIdx.x; i < n; i += gridDim.x) {
        const int row = redolist[i];
        const float* xr = x + (size_t)row * ND;
        double h = 0.0;
        for (int k = 0; k < ND; ++k)
            h = fma((double)xr[k], (double)w1[(size_t)k * NH + t], h);
        h += (double)b1[t];
        h = h > 0.0 ? h : 0.0;
        double p0 = h * (double)w2[t * 3 + 0];
        double p1 = h * (double)w2[t * 3 + 1];
        double p2 = h * (double)w2[t * 3 + 2];
        #pragma unroll
        for (int m = 32; m >= 1; m >>= 1) {
            p0 += __shfl_xor(p0, m);
            p1 += __shfl_xor(p1, m);
            p2 += __shfl_xor(p2, m);
        }
        if ((t & 63) == 0) {
            red[t >> 6][0] = p0; red[t >> 6][1] = p1; red[t >> 6][2] = p2;
        }
        __syncthreads();
        if (t == 0) {
            double best = 0.0; int be = 0;
            #pragma unroll
            for (int e = 0; e < NE; ++e) {
                const double z = red[0][e] + red[1][e] + (double)b2[e]
                               + (double)gum[(size_t)row * 3 + e];
                if (e == 0 || z > best) { best = z; be = e; }
            }
            const int pos = atomicAdd(&counts[be], 1);
            rowlist[be * NB + pos] = row;
        }
        __syncthreads();
    }
}

// ---------------------------------------------------------------------------
// head: grouped bf16 MFMA GEMM, BM=64 x BN=512(padded NC), same burst idiom.
// Waves split N (128 cols each); all waves share the 64-row A tile.
// ---------------------------------------------------------------------------
__global__ __launch_bounds__(256) void head_kernel(
    const float* __restrict__ x, const float2* __restrict__ murs,
    const short* __restrict__ hwbT, const float* __restrict__ hbias,
    const int* __restrict__ counts, const int* __restrict__ rowlist,
    float* __restrict__ out)
{
    const int e = blockIdx.z;
    const int cnt = counts[e];
    const int rc0 = blockIdx.y * 64;
    if (rc0 >= cnt) return;

    __shared__ __align__(16) short As[64 * 392];
    __shared__ __align__(16) short Bs[2 * 16384];  // 2 x (512c x 32k)
    __shared__ float hbs[NCP];
    __shared__ int rows_s[64];

    const int t = threadIdx.x;
    const int w = t >> 6, l = t & 63;
    const int g = l >> 4, lm = l & 15;
    const int sr = t >> 2, sq = t & 3;

    const int ridx = rc0 + sr;
    const bool av = ridx < cnt;
    const int arow = av ? rowlist[e * NB + ridx] : 0;
    float mu = 0.f, rs = 0.f;
    if (av) { const float2 mr = murs[arow]; mu = mr.x; rs = mr.y; }
    const float nm = -mu * rs;
    const float* xrow = x + (size_t)arow * ND + sq * 96;

    if (t < 64) {
        const int ri = rc0 + t;
        rows_s[t] = (ri < cnt) ? rowlist[e * NB + ri] : -1;
    }
    hbs[t] = hbias[e * NCP + t];
    hbs[t + 256] = hbias[e * NCP + t + 256];
    const short* hwe = hwbT + (size_t)e * NCP * ND;

    v4f acc[4][8];
    #pragma unroll
    for (int i = 0; i < 4; ++i)
        #pragma unroll
        for (int j = 0; j < 8; ++j) acc[i][j] = (v4f)(0.f);

    int cur = 0;
    #pragma unroll 1
    for (int hf = 0; hf < 2; ++hf) {
        const int kh = hf * 384;
        float4 xa[12];
        #pragma unroll
        for (int i = 0; i < 12; ++i)
            xa[i] = av ? *(const float4*)(xrow + kh + i * 4)
                       : make_float4(0.f, 0.f, 0.f, 0.f);
        #pragma unroll
        for (int i = 0; i < 8; ++i) {
            const int crow = w * 128 + i * 16 + (l >> 2);
            const int off = __builtin_amdgcn_readfirstlane(
                cur * 16384 + (w * 128 + i * 16) * 32);
            GLD16(hwe + (size_t)crow * ND + kh + (l & 3) * 8, Bs + off);
        }
        __syncthreads();   // prev-half LDS reads done; xa + prime drained
        float4 xb[12];
        #pragma unroll
        for (int i = 0; i < 12; ++i)
            xb[i] = av ? *(const float4*)(xrow + kh + 48 + i * 4)
                       : make_float4(0.f, 0.f, 0.f, 0.f);
        #pragma unroll
        for (int i = 0; i < 6; ++i) {
            const float4 a = xa[2*i], b = xa[2*i+1];
            v8s av8;
            av8[0]=f2bf(fmaf(a.x,rs,nm)); av8[1]=f2bf(fmaf(a.y,rs,nm));
            av8[2]=f2bf(fmaf(a.z,rs,nm)); av8[3]=f2bf(fmaf(a.w,rs,nm));
            av8[4]=f2bf(fmaf(b.x,rs,nm)); av8[5]=f2bf(fmaf(b.y,rs,nm));
            av8[6]=f2bf(fmaf(b.z,rs,nm)); av8[7]=f2bf(fmaf(b.w,rs,nm));
            *(v8s*)&As[sr * 392 + sq * 96 + i * 8] = av8;
        }
        #pragma unroll
        for (int i = 0; i < 6; ++i) {
            const float4 a = xb[2*i], b = xb[2*i+1];
            v8s av8;
            av8[0]=f2bf(fmaf(a.x,rs,nm)); av8[1]=f2bf(fmaf(a.y,rs,nm));
            av8[2]=f2bf(fmaf(a.z,rs,nm)); av8[3]=f2bf(fmaf(a.w,rs,nm));
            av8[4]=f2bf(fmaf(b.x,rs,nm)); av8[5]=f2bf(fmaf(b.y,rs,nm));
            av8[6]=f2bf(fmaf(b.z,rs,nm)); av8[7]=f2bf(fmaf(b.w,rs,nm));
            *(v8s*)&As[sr * 392 + sq * 96 + 48 + i * 8] = av8;
        }
        __syncthreads();   // A ready, B tile0 landed
        #pragma unroll 1
        for (int ks = 0; ks < 12; ++ks) {
            if (ks < 11) {
                #pragma unroll
                for (int i = 0; i < 8; ++i) {
                    const int crow = w * 128 + i * 16 + (l >> 2);
                    const int off = __builtin_amdgcn_readfirstlane(
                        (cur ^ 1) * 16384 + (w * 128 + i * 16) * 32);
                    GLD16(hwe + (size_t)crow * ND + kh + (ks + 1) * 32 + (l & 3) * 8,
                          Bs + off);
                }
            }
            v8s af[4], bf_[8];
            #pragma unroll
            for (int mf = 0; mf < 4; ++mf)
                af[mf] = *(const v8s*)&As[(mf * 16 + lm) * 392 + ks * 32 + g * 8];
            #pragma unroll
            for (int nf = 0; nf < 8; ++nf) {
                const int c = w * 128 + nf * 16 + lm;
                bf_[nf] = *(const v8s*)&Bs[cur * 16384 + c * 32 + (g ^ ((c >> 1) & 3)) * 8];
            }
            #pragma unroll
            for (int mf = 0; mf < 4; ++mf)
                #pragma unroll
                for (int nf = 0; nf < 8; ++nf)
                    acc[mf][nf] = __builtin_amdgcn_mfma_f32_16x16x32_bf16(
                        af[mf], bf_[nf], acc[mf][nf], 0, 0, 0);
            __syncthreads();
            cur ^= 1;
        }
    }

    #pragma unroll
    for (int mf = 0; mf < 4; ++mf) {
        #pragma unroll
        for (int r = 0; r < 4; ++r) {
            const int rl = mf * 16 + g * 4 + r;
            const int orow = rows_s[rl];
            if (orow < 0) continue;
            float* op = out + (size_t)orow * NC;
            #pragma unroll
            for (int nf = 0; nf < 8; ++nf) {
                const int c = w * 128 + nf * 16 + lm;
                if (c < NC) op[c] = acc[mf][nf][r] + hbs[c];
            }
        }
    }
}

extern "C" void kernel_launch(void* const* d_in, const int* in_sizes, int n_in,
                              void* d_out, int out_size, void* d_ws, size_t ws_size,
                              hipStream_t stream) {
    const float* x     = (const float*)d_in[0];
    const float* gum   = (const float*)d_in[1];
    const float* w1    = (const float*)d_in[2];
    const float* b1    = (const float*)d_in[3];
    const float* w2    = (const float*)d_in[4];
    const float* b2    = (const float*)d_in[5];
    const float* gamma = (const float*)d_in[6];
    const float* beta  = (const float*)d_in[7];
    const float* hw    = (const float*)d_in[8];
    const float* hb    = (const float*)d_in[9];
    float* out = (float*)d_out;

    char* ws = (char*)d_ws;
    int*    counts   = (int*)ws;                    // 16 B (zeroed every call)
    float2* murs     = (float2*)(ws + 256);         // 262144 B
    int*    rowlist  = (int*)(ws + 262400);         // 393216 B
    int*    redolist = (int*)(ws + 655616);         // 131072 B
    float*  hbias    = (float*)(ws + 786688);       // 6144 B
    float*  bpart    = (float*)(ws + 792832);       // 98304 B
    short*  w1bT     = (short*)(ws + 891136);       // 196608 B
    short*  hwbT     = (short*)(ws + 1087744);      // 2359296 B -> end 3447040

    hipMemsetAsync(counts, 0, 16, stream);
    prep_kernel<<<624, 256, 0, stream>>>(hw, gamma, w1, hwbT, w1bT);
    bias_part_kernel<<<dim3(3, 16), 256, 0, stream>>>(hw, beta, bpart);
    bias_comb_kernel<<<3, 256, 0, stream>>>(bpart, hb, hbias);
    selector_kernel<<<NB / 64, 256, 0, stream>>>(x, gum, w1bT, b1, w2, b2,
                                                 murs, counts, rowlist, redolist);
    redo_kernel<<<512, 128, 0, stream>>>(x, gum, w1, b1, w2, b2,
                                         counts, rowlist, redolist);
    head_kernel<<<dim3(1, NB / 64, NE), 256, 0, stream>>>(
        x, murs, hwbT, hbias, counts, rowlist, out);
}

// Round 6
// 301.975 us; speedup vs baseline: 2.6774x; 1.7614x over previous
//
#include <hip/hip_runtime.h>
#include <hip/hip_bf16.h>
#include <math.h>

#define NB 32768
#define ND 768
#define NC 474
#define NCP 512
#define NE 3
#define NH 128
#define GAP_THR 0.06f

typedef short v8s __attribute__((ext_vector_type(8)));
typedef float v4f __attribute__((ext_vector_type(4)));
typedef unsigned long long u64;

#define GLD16(gp, lp) __builtin_amdgcn_global_load_lds( \
    (const __attribute__((address_space(1))) void*)(gp), \
    (__attribute__((address_space(3))) void*)(lp), 16, 0, 0)

static __device__ __forceinline__ short f2bf(float f) {
    __hip_bfloat16 h = __float2bfloat16(f);
    return *reinterpret_cast<short*>(&h);
}

// ---------------------------------------------------------------------------
// prep: hwbT[e][c][k] = bf16(gamma[e][k]*hw[e][k][c]) transposed + slot-swizzled;
//       w1bT[c][k]    = bf16(w1[k][c]) same layout.
// Swizzle: within each 32-k (64B) group, 16B slot s -> s ^ ((c>>1)&3).
// ---------------------------------------------------------------------------
__global__ __launch_bounds__(256) void prep_kernel(
    const float* __restrict__ hw, const float* __restrict__ gamma,
    const float* __restrict__ w1,
    short* __restrict__ hwbT, short* __restrict__ w1bT)
{
    __shared__ float T[32][72];
    const int t = threadIdx.x;
    const int id = blockIdx.x;
    const float* src; short* dst; int stride, ncs; int e = 0, cc, kc;
    bool is_exp = (id < 576);
    if (is_exp) {
        e = id / 192; const int r2 = id % 192; cc = r2 / 24; kc = r2 % 24;
        src = hw + (size_t)e * ND * NC; stride = NC; ncs = NC;
        dst = hwbT + (size_t)e * NCP * ND;
    } else {
        const int j = id - 576; cc = j / 24; kc = j % 24;
        src = w1; stride = NH; ncs = NH; dst = w1bT;
    }
    const int c0 = cc * 64, k0 = kc * 32;
    {
        const int kl = t >> 3, c8 = (t & 7) * 8;
        const float g = is_exp ? gamma[e * ND + k0 + kl] : 1.f;
        #pragma unroll
        for (int j = 0; j < 8; ++j) {
            const int cg = c0 + c8 + j;
            const float v = (cg < ncs) ? src[(size_t)(k0 + kl) * stride + cg] : 0.f;
            T[kl][c8 + j] = v * g;
        }
    }
    __syncthreads();
    {
        const int cl = t >> 2, q = t & 3;
        const int cg = c0 + cl;
        const int sp = q ^ ((cg >> 1) & 3);
        union { short s[8]; int4 v; } u;
        #pragma unroll
        for (int j = 0; j < 8; ++j) u.s[j] = f2bf(T[q * 8 + j][cl]);
        *(int4*)(dst + (size_t)cg * ND + k0 + sp * 8) = u.v;
    }
}

// bias partials: bpart[e][kc][c] = sum_{k in chunk} beta[e][k]*hw[e][k][c]
__global__ __launch_bounds__(256) void bias_part_kernel(
    const float* __restrict__ hw, const float* __restrict__ beta,
    float* __restrict__ bpart)
{
    const int e = blockIdx.x, kc = blockIdx.y, t = threadIdx.x;
    const float* he = hw + (size_t)e * ND * NC;
    float a0 = 0.f, a1 = 0.f;
    const int c1 = t + 256;
    for (int k = kc * 48; k < kc * 48 + 48; ++k) {
        const float b = beta[e * ND + k];
        const float* row = he + (size_t)k * NC;
        a0 = fmaf(b, row[t], a0);
        if (c1 < NC) a1 = fmaf(b, row[c1], a1);
    }
    float* bp = bpart + (size_t)(e * 16 + kc) * NCP;
    bp[t] = a0;
    bp[c1] = (c1 < NC) ? a1 : 0.f;
}

__global__ __launch_bounds__(256) void bias_comb_kernel(
    const float* __restrict__ bpart, const float* __restrict__ hb,
    float* __restrict__ hbias)
{
    const int e = blockIdx.x, t = threadIdx.x;
    #pragma unroll
    for (int h = 0; h < 2; ++h) {
        const int c = t + h * 256;
        float s = 0.f;
        for (int kc = 0; kc < 16; ++kc)
            s += bpart[(size_t)(e * 16 + kc) * NCP + c];
        hbias[e * NCP + c] = (c < NC) ? hb[e * NC + c] + s : 0.f;
    }
}

// ---------------------------------------------------------------------------
// selector: 64 rows/block, burst A-stage + double-buffered B (GLD16).
// Epilogue: LN stats, logits, gap cascade; bucket append via ONE packed
// 64-bit atomic per block (4x16-bit fields), broadcast via __shfl (no LDS).
// ---------------------------------------------------------------------------
__global__ __launch_bounds__(256) void selector_kernel(
    const float* __restrict__ x, const float* __restrict__ gum,
    const short* __restrict__ w1bT, const float* __restrict__ b1,
    const float* __restrict__ w2, const float* __restrict__ b2,
    float2* __restrict__ murs, u64* __restrict__ counts,
    int* __restrict__ rowlist, int* __restrict__ redolist)
{
    __shared__ __align__(16) short As[64 * 392];   // 64 rows x 384k, stride 392
    __shared__ __align__(16) short Bs[2 * 4096];   // 2 x (128c x 32k)
    __shared__ float b1s[NH];
    __shared__ float w2s[NH * 3];
    __shared__ int besm[64];

    const int t = threadIdx.x;
    const int row0 = blockIdx.x * 64;
    const int w = t >> 6, l = t & 63;
    const int g = l >> 4, lm = l & 15;
    const int sr = t >> 2, sq = t & 3;

    if (t < NH) {
        b1s[t] = b1[t];
        w2s[t*3+0] = w2[t*3+0]; w2s[t*3+1] = w2[t*3+1]; w2s[t*3+2] = w2[t*3+2];
    }

    v4f acc[8];
    #pragma unroll
    for (int i = 0; i < 8; ++i) acc[i] = (v4f)(0.f);

    const float* xrow = x + (size_t)(row0 + sr) * ND + sq * 96;
    float s1 = 0.f, s2 = 0.f;
    int cur = 0;

    #pragma unroll 1
    for (int hf = 0; hf < 2; ++hf) {
        const int kh = hf * 384;
        float4 xv[24];
        #pragma unroll
        for (int i = 0; i < 24; ++i)
            xv[i] = *(const float4*)(xrow + kh + i * 4);
        #pragma unroll
        for (int i = 0; i < 2; ++i) {
            const int crow = w * 32 + i * 16 + (l >> 2);
            const int off = __builtin_amdgcn_readfirstlane(
                cur * 4096 + (w * 32 + i * 16) * 32);
            GLD16(w1bT + (size_t)crow * ND + kh + (l & 3) * 8, Bs + off);
        }
        __syncthreads();
        #pragma unroll
        for (int i = 0; i < 12; ++i) {
            const float4 a = xv[2*i], b = xv[2*i+1];
            s1 += a.x+a.y+a.z+a.w + b.x+b.y+b.z+b.w;
            s2 += a.x*a.x+a.y*a.y+a.z*a.z+a.w*a.w
                + b.x*b.x+b.y*b.y+b.z*b.z+b.w*b.w;
            v8s av;
            av[0]=f2bf(a.x); av[1]=f2bf(a.y); av[2]=f2bf(a.z); av[3]=f2bf(a.w);
            av[4]=f2bf(b.x); av[5]=f2bf(b.y); av[6]=f2bf(b.z); av[7]=f2bf(b.w);
            *(v8s*)&As[sr * 392 + sq * 96 + i * 8] = av;
        }
        __syncthreads();
        #pragma unroll 1
        for (int ks = 0; ks < 12; ++ks) {
            if (ks < 11) {
                #pragma unroll
                for (int i = 0; i < 2; ++i) {
                    const int crow = w * 32 + i * 16 + (l >> 2);
                    const int off = __builtin_amdgcn_readfirstlane(
                        (cur ^ 1) * 4096 + (w * 32 + i * 16) * 32);
                    GLD16(w1bT + (size_t)crow * ND + kh + (ks + 1) * 32 + (l & 3) * 8,
                          Bs + off);
                }
            }
            const v8s a = *(const v8s*)&As[(w * 16 + lm) * 392 + ks * 32 + g * 8];
            #pragma unroll
            for (int nf = 0; nf < 8; ++nf) {
                const int c = nf * 16 + lm;
                const v8s bv = *(const v8s*)&Bs[cur * 4096 + c * 32 + (g ^ ((c >> 1) & 3)) * 8];
                acc[nf] = __builtin_amdgcn_mfma_f32_16x16x32_bf16(a, bv, acc[nf], 0, 0, 0);
            }
            __syncthreads();
            cur ^= 1;
        }
    }

    // LN stats
    {
        float r1 = s1 + __shfl_xor(s1, 1);
        float r2 = s2 + __shfl_xor(s2, 1);
        r1 += __shfl_xor(r1, 2);
        r2 += __shfl_xor(r2, 2);
        if (sq == 0) {
            const float mu = r1 * (1.f/768.f);
            const float var = r2 * (1.f/768.f) - mu * mu;
            murs[row0 + sr] = make_float2(mu, rsqrtf(var + 1e-5f));
        }
    }

    // logits = relu(h + b1) @ w2, reduced across the 16 col-lanes
    float p[4][3];
    #pragma unroll
    for (int r = 0; r < 4; ++r) { p[r][0]=0.f; p[r][1]=0.f; p[r][2]=0.f; }
    #pragma unroll
    for (int nf = 0; nf < 8; ++nf) {
        const int c = nf * 16 + lm;
        const float bb = b1s[c];
        const float wa = w2s[c*3], wb = w2s[c*3+1], wcc = w2s[c*3+2];
        #pragma unroll
        for (int r = 0; r < 4; ++r) {
            const float h = fmaxf(acc[nf][r] + bb, 0.f);
            p[r][0] = fmaf(h, wa,  p[r][0]);
            p[r][1] = fmaf(h, wb,  p[r][1]);
            p[r][2] = fmaf(h, wcc, p[r][2]);
        }
    }
    #pragma unroll
    for (int m = 1; m < 16; m <<= 1) {
        #pragma unroll
        for (int r = 0; r < 4; ++r) {
            p[r][0] += __shfl_xor(p[r][0], m);
            p[r][1] += __shfl_xor(p[r][1], m);
            p[r][2] += __shfl_xor(p[r][2], m);
        }
    }
    if (lm == 0) {
        const float bb0 = b2[0], bb1 = b2[1], bb2 = b2[2];
        #pragma unroll
        for (int r = 0; r < 4; ++r) {
            const int rl = w * 16 + g * 4 + r;
            const int grow = row0 + rl;
            const float z0 = p[r][0] + bb0 + gum[grow*3+0];
            const float z1 = p[r][1] + bb1 + gum[grow*3+1];
            const float z2 = p[r][2] + bb2 + gum[grow*3+2];
            int be = 0; float best = z0;
            if (z1 > best) { best = z1; be = 1; }
            if (z2 > best) { best = z2; be = 2; }
            const float second = (be==0) ? fmaxf(z1,z2) : (be==1) ? fmaxf(z0,z2) : fmaxf(z0,z1);
            besm[rl] = (best - second < GAP_THR) ? 3 : be;
        }
    }
    __syncthreads();

    // wave 0: ballot-aggregate 64 decisions -> ONE packed atomic; shfl broadcast
    if (w == 0) {
        const int be = besm[l];
        const u64 m0 = __ballot(be == 0);
        const u64 m1 = __ballot(be == 1);
        const u64 m2 = __ballot(be == 2);
        const u64 m3 = __ballot(be == 3);
        u64 old = 0;
        if (l == 0) {
            const u64 add = (u64)__popcll(m0)
                          | ((u64)__popcll(m1) << 16)
                          | ((u64)__popcll(m2) << 32)
                          | ((u64)__popcll(m3) << 48);
            old = atomicAdd(counts, add);
        }
        // broadcast 64-bit old value from lane 0 via two 32-bit shuffles
        const int blo = __shfl((int)(old & 0xFFFFFFFFull), 0);
        const int bhi = __shfl((int)(old >> 32), 0);
        old = ((u64)(unsigned)bhi << 32) | (u64)(unsigned)blo;
        const u64 mym = (be == 0) ? m0 : (be == 1) ? m1 : (be == 2) ? m2 : m3;
        const u64 below = (l == 63) ? 0x7FFFFFFFFFFFFFFFull : ((1ull << l) - 1ull);
        const int rank = __popcll(mym & below);
        const int base = (int)((old >> (16 * be)) & 0xFFFFull);
        const int idx = base + rank;
        const int grow = row0 + l;
        if (be < 3) {
            if ((unsigned)idx < NB) rowlist[be * NB + idx] = grow;
        } else {
            if ((unsigned)idx < NB) redolist[idx] = grow;
        }
    }
}

// fp64 redo for ambiguous rows
__global__ __launch_bounds__(128) void redo_kernel(
    const float* __restrict__ x, const float* __restrict__ gum,
    const float* __restrict__ w1, const float* __restrict__ b1,
    const float* __restrict__ w2, const float* __restrict__ b2,
    u64* __restrict__ counts, int* __restrict__ rowlist,
    const int* __restrict__ redolist)
{
    const int t = threadIdx.x;
    int n = (int)((*counts >> 48) & 0xFFFFull);
    if (n > NB) n = NB;
    __shared__ double red[2][3];
    for (int i = blockIdx.x; i < n; i += gridDim.x) {
        const int row = redolist[i];
        const float* xr = x + (size_t)row * ND;
        double h = 0.0;
        for (int k = 0; k < ND; ++k)
            h = fma((double)xr[k], (double)w1[(size_t)k * NH + t], h);
        h += (double)b1[t];
        h = h > 0.0 ? h : 0.0;
        double p0 = h * (double)w2[t * 3 + 0];
        double p1 = h * (double)w2[t * 3 + 1];
        double p2 = h * (double)w2[t * 3 + 2];
        #pragma unroll
        for (int m = 32; m >= 1; m >>= 1) {
            p0 += __shfl_xor(p0, m);
            p1 += __shfl_xor(p1, m);
            p2 += __shfl_xor(p2, m);
        }
        if ((t & 63) == 0) {
            red[t >> 6][0] = p0; red[t >> 6][1] = p1; red[t >> 6][2] = p2;
        }
        __syncthreads();
        if (t == 0) {
            double best = 0.0; int be = 0;
            #pragma unroll
            for (int e = 0; e < NE; ++e) {
                const double z = red[0][e] + red[1][e] + (double)b2[e]
                               + (double)gum[(size_t)row * 3 + e];
                if (e == 0 || z > best) { best = z; be = e; }
            }
            const u64 old = atomicAdd(counts, 1ull << (16 * be));
            const int pos = (int)((old >> (16 * be)) & 0xFFFFull);
            if ((unsigned)pos < NB) rowlist[be * NB + pos] = row;
        }
        __syncthreads();
    }
}

// ---------------------------------------------------------------------------
// head: grouped bf16 MFMA GEMM, BM=64 x BN=512(padded NC), burst idiom.
// ---------------------------------------------------------------------------
__global__ __launch_bounds__(256) void head_kernel(
    const float* __restrict__ x, const float2* __restrict__ murs,
    const short* __restrict__ hwbT, const float* __restrict__ hbias,
    const u64* __restrict__ counts, const int* __restrict__ rowlist,
    float* __restrict__ out)
{
    const int e = blockIdx.z;
    int cnt = (int)((*counts >> (16 * e)) & 0xFFFFull);
    if (cnt > NB) cnt = NB;
    const int rc0 = blockIdx.y * 64;
    if (rc0 >= cnt) return;

    __shared__ __align__(16) short As[64 * 392];
    __shared__ __align__(16) short Bs[2 * 16384];
    __shared__ float hbs[NCP];
    __shared__ int rows_s[64];

    const int t = threadIdx.x;
    const int w = t >> 6, l = t & 63;
    const int g = l >> 4, lm = l & 15;
    const int sr = t >> 2, sq = t & 3;

    const int ridx = rc0 + sr;
    const bool av = ridx < cnt;
    int arow = av ? rowlist[e * NB + ridx] : 0;
    if ((unsigned)arow >= NB) arow = 0;
    float mu = 0.f, rs = 0.f;
    if (av) { const float2 mr = murs[arow]; mu = mr.x; rs = mr.y; }
    const float nm = -mu * rs;
    const float* xrow = x + (size_t)arow * ND + sq * 96;

    if (t < 64) {
        const int ri = rc0 + t;
        int rr = (ri < cnt) ? rowlist[e * NB + ri] : -1;
        if (rr >= NB) rr = -1;
        rows_s[t] = rr;
    }
    hbs[t] = hbias[e * NCP + t];
    hbs[t + 256] = hbias[e * NCP + t + 256];
    const short* hwe = hwbT + (size_t)e * NCP * ND;

    v4f acc[4][8];
    #pragma unroll
    for (int i = 0; i < 4; ++i)
        #pragma unroll
        for (int j = 0; j < 8; ++j) acc[i][j] = (v4f)(0.f);

    int cur = 0;
    #pragma unroll 1
    for (int hf = 0; hf < 2; ++hf) {
        const int kh = hf * 384;
        float4 xa[12];
        #pragma unroll
        for (int i = 0; i < 12; ++i)
            xa[i] = av ? *(const float4*)(xrow + kh + i * 4)
                       : make_float4(0.f, 0.f, 0.f, 0.f);
        #pragma unroll
        for (int i = 0; i < 8; ++i) {
            const int crow = w * 128 + i * 16 + (l >> 2);
            const int off = __builtin_amdgcn_readfirstlane(
                cur * 16384 + (w * 128 + i * 16) * 32);
            GLD16(hwe + (size_t)crow * ND + kh + (l & 3) * 8, Bs + off);
        }
        __syncthreads();
        float4 xb[12];
        #pragma unroll
        for (int i = 0; i < 12; ++i)
            xb[i] = av ? *(const float4*)(xrow + kh + 48 + i * 4)
                       : make_float4(0.f, 0.f, 0.f, 0.f);
        #pragma unroll
        for (int i = 0; i < 6; ++i) {
            const float4 a = xa[2*i], b = xa[2*i+1];
            v8s av8;
            av8[0]=f2bf(fmaf(a.x,rs,nm)); av8[1]=f2bf(fmaf(a.y,rs,nm));
            av8[2]=f2bf(fmaf(a.z,rs,nm)); av8[3]=f2bf(fmaf(a.w,rs,nm));
            av8[4]=f2bf(fmaf(b.x,rs,nm)); av8[5]=f2bf(fmaf(b.y,rs,nm));
            av8[6]=f2bf(fmaf(b.z,rs,nm)); av8[7]=f2bf(fmaf(b.w,rs,nm));
            *(v8s*)&As[sr * 392 + sq * 96 + i * 8] = av8;
        }
        #pragma unroll
        for (int i = 0; i < 6; ++i) {
            const float4 a = xb[2*i], b = xb[2*i+1];
            v8s av8;
            av8[0]=f2bf(fmaf(a.x,rs,nm)); av8[1]=f2bf(fmaf(a.y,rs,nm));
            av8[2]=f2bf(fmaf(a.z,rs,nm)); av8[3]=f2bf(fmaf(a.w,rs,nm));
            av8[4]=f2bf(fmaf(b.x,rs,nm)); av8[5]=f2bf(fmaf(b.y,rs,nm));
            av8[6]=f2bf(fmaf(b.z,rs,nm)); av8[7]=f2bf(fmaf(b.w,rs,nm));
            *(v8s*)&As[sr * 392 + sq * 96 + 48 + i * 8] = av8;
        }
        __syncthreads();
        #pragma unroll 1
        for (int ks = 0; ks < 12; ++ks) {
            if (ks < 11) {
                #pragma unroll
                for (int i = 0; i < 8; ++i) {
                    const int crow = w * 128 + i * 16 + (l >> 2);
                    const int off = __builtin_amdgcn_readfirstlane(
                        (cur ^ 1) * 16384 + (w * 128 + i * 16) * 32);
                    GLD16(hwe + (size_t)crow * ND + kh + (ks + 1) * 32 + (l & 3) * 8,
                          Bs + off);
                }
            }
            v8s af[4], bf_[8];
            #pragma unroll
            for (int mf = 0; mf < 4; ++mf)
                af[mf] = *(const v8s*)&As[(mf * 16 + lm) * 392 + ks * 32 + g * 8];
            #pragma unroll
            for (int nf = 0; nf < 8; ++nf) {
                const int c = w * 128 + nf * 16 + lm;
                bf_[nf] = *(const v8s*)&Bs[cur * 16384 + c * 32 + (g ^ ((c >> 1) & 3)) * 8];
            }
            #pragma unroll
            for (int mf = 0; mf < 4; ++mf)
                #pragma unroll
                for (int nf = 0; nf < 8; ++nf)
                    acc[mf][nf] = __builtin_amdgcn_mfma_f32_16x16x32_bf16(
                        af[mf], bf_[nf], acc[mf][nf], 0, 0, 0);
            __syncthreads();
            cur ^= 1;
        }
    }

    #pragma unroll
    for (int mf = 0; mf < 4; ++mf) {
        #pragma unroll
        for (int r = 0; r < 4; ++r) {
            const int rl = mf * 16 + g * 4 + r;
            const int orow = rows_s[rl];
            if (orow < 0) continue;
            float* op = out + (size_t)orow * NC;
            #pragma unroll
            for (int nf = 0; nf < 8; ++nf) {
                const int c = w * 128 + nf * 16 + lm;
                if (c < NC) op[c] = acc[mf][nf][r] + hbs[c];
            }
        }
    }
}

extern "C" void kernel_launch(void* const* d_in, const int* in_sizes, int n_in,
                              void* d_out, int out_size, void* d_ws, size_t ws_size,
                              hipStream_t stream) {
    const float* x     = (const float*)d_in[0];
    const float* gum   = (const float*)d_in[1];
    const float* w1    = (const float*)d_in[2];
    const float* b1    = (const float*)d_in[3];
    const float* w2    = (const float*)d_in[4];
    const float* b2    = (const float*)d_in[5];
    const float* gamma = (const float*)d_in[6];
    const float* beta  = (const float*)d_in[7];
    const float* hw    = (const float*)d_in[8];
    const float* hb    = (const float*)d_in[9];
    float* out = (float*)d_out;

    char* ws = (char*)d_ws;
    u64*    counts   = (u64*)ws;                    // packed 4x16-bit counters
    float2* murs     = (float2*)(ws + 256);         // 262144 B
    int*    rowlist  = (int*)(ws + 262400);         // 393216 B
    int*    redolist = (int*)(ws + 655616);         // 131072 B
    float*  hbias    = (float*)(ws + 786688);       // 6144 B
    float*  bpart    = (float*)(ws + 792832);       // 98304 B
    short*  w1bT     = (short*)(ws + 891136);       // 196608 B
    short*  hwbT     = (short*)(ws + 1087744);      // 2359296 B

    hipMemsetAsync(counts, 0, 16, stream);
    prep_kernel<<<624, 256, 0, stream>>>(hw, gamma, w1, hwbT, w1bT);
    bias_part_kernel<<<dim3(3, 16), 256, 0, stream>>>(hw, beta, bpart);
    bias_comb_kernel<<<3, 256, 0, stream>>>(bpart, hb, hbias);
    selector_kernel<<<NB / 64, 256, 0, stream>>>(x, gum, w1bT, b1, w2, b2,
                                                 murs, counts, rowlist, redolist);
    redo_kernel<<<512, 128, 0, stream>>>(x, gum, w1, b1, w2, b2,
                                         counts, rowlist, redolist);
    head_kernel<<<dim3(1, NB / 64, NE), 256, 0, stream>>>(
        x, murs, hwbT, hbias, counts, rowlist, out);
}